// Round 6
// baseline (679.217 us; speedup 1.0000x reference)
//
#include <hip/hip_runtime.h>
#include <stdint.h>

#define N_NODES 50000
#define N_EDGES 600000
#define N_REL   8
#define KDIM    1152                      // 8 relations * 128 + 128 (root/self)
#define NSEG    (N_NODES * N_REL)         // 400000 (node,rel) segments
#define NB_SEG  ((NSEG + 255) / 256)      // 1563

typedef short v8s __attribute__((ext_vector_type(8)));
typedef float v4f __attribute__((ext_vector_type(4)));
typedef unsigned short u16;
typedef unsigned int   u32;

__device__ __forceinline__ float bf2f(u16 u) {
    union { u32 i; float f; } t; t.i = ((u32)u) << 16; return t.f;
}
__device__ __forceinline__ u16 f2bf(float f) {
    union { float f; u32 i; } t; t.f = f;
    u32 lsb = (t.i >> 16) & 1u;
    t.i += 0x7fffu + lsb;            // round-to-nearest-even
    return (u16)(t.i >> 16);
}
__device__ __forceinline__ float load_f(const void* p, int i, int fl) {
    return fl ? bf2f(((const u16*)p)[i]) : ((const float*)p)[i];
}

// ---------- dtype detection: bf16 vs f32 ----------
__global__ void k_detect(const u32* __restrict__ x, int* __restrict__ flag) {
    __shared__ int cnt;
    int tid = threadIdx.x;
    if (tid == 0) cnt = 0;
    __syncthreads();
    int local = 0;
    for (int j = 0; j < 4; ++j) {
        u32 e = (x[tid * 4 + j] >> 7) & 0xffu;
        if (e >= 112u && e < 144u) local++;
    }
    atomicAdd(&cnt, local);
    __syncthreads();
    if (tid == 0) *flag = (cnt >= 512) ? 1 : 0;   // 1 = bf16, 0 = f32
}

__global__ void k_convert(const void* __restrict__ src, u16* __restrict__ dst, int n,
                          const int* __restrict__ flag) {
    int i = blockIdx.x * 256 + threadIdx.x;
    if (i >= n) return;
    if (*flag) dst[i] = ((const u16*)src)[i];
    else       dst[i] = f2bf(((const float*)src)[i]);
}

// ---------- weight prep ----------
// Wbig[l][j][k]: k<1024 -> W_l[k/128][k%128][j]; k>=1024 -> root_l[k-1024][j]
__global__ void k_prep_w(const void* __restrict__ W1, const void* __restrict__ r1,
                         const void* __restrict__ b1, const void* __restrict__ W2,
                         const void* __restrict__ r2, const void* __restrict__ b2,
                         const int* __restrict__ flag,
                         u16* __restrict__ Wbig, u16* __restrict__ bc) {
    int o = blockIdx.x * 256 + threadIdx.x;
    int fl = *flag;
    if (o < 2 * 128 * KDIM) {
        int l = o / (128 * KDIM);
        int rem = o - l * (128 * KDIM);
        int j = rem / KDIM, k = rem - j * KDIM;
        float v;
        if (k < 1024) {
            int r = k >> 7, kk = k & 127;
            v = load_f(l ? W2 : W1, r * 16384 + kk * 128 + j, fl);
        } else {
            v = load_f(l ? r2 : r1, (k - 1024) * 128 + j, fl);
        }
        Wbig[o] = f2bf(v);
    } else if (o < 2 * 128 * KDIM + 256) {
        int o2 = o - 2 * 128 * KDIM;
        bc[o2] = f2bf(load_f((o2 >> 7) ? b2 : b1, o2 & 127, fl));
    }
}

// ---------- graph prep: relation-segmented CSR ----------
__global__ void k_zero_i32(int* __restrict__ p, int n) {
    int i = blockIdx.x * 256 + threadIdx.x;
    if (i < n) p[i] = 0;
}

__global__ void k_count8(const int* __restrict__ ei, const int* __restrict__ et,
                         int* __restrict__ cnt8) {
    int i = blockIdx.x * 256 + threadIdx.x;
    if (i >= N_EDGES) return;
    atomicAdd(&cnt8[ei[N_EDGES + i] * N_REL + et[i]], 1);
}

// per-block inclusive scan over n elems -> out[idx+1], block totals -> psum
__global__ void k_scan1(const int* __restrict__ in, int* __restrict__ out,
                        int* __restrict__ psum, int n) {
    __shared__ int lds[256];
    int tid = threadIdx.x;
    int idx = blockIdx.x * 256 + tid;
    int v = (idx < n) ? in[idx] : 0;
    lds[tid] = v;
    __syncthreads();
    for (int off = 1; off < 256; off <<= 1) {
        int t = (tid >= off) ? lds[tid - off] : 0;
        __syncthreads();
        lds[tid] += t;
        __syncthreads();
    }
    if (idx < n) out[idx + 1] = lds[tid];
    if (tid == 255) psum[blockIdx.x] = lds[255];
}

// single-block exclusive scan over n (<= a few K) elems, in-place, 1024 thr
__global__ void k_scan2big(int* __restrict__ psum, int n) {
    __shared__ int lds[1024];
    __shared__ int carry;
    int tid = threadIdx.x;
    if (tid == 0) carry = 0;
    __syncthreads();
    for (int base = 0; base < n; base += 1024) {
        int idx = base + tid;
        int v = (idx < n) ? psum[idx] : 0;
        lds[tid] = v;
        __syncthreads();
        for (int off = 1; off < 1024; off <<= 1) {
            int t = (tid >= off) ? lds[tid - off] : 0;
            __syncthreads();
            lds[tid] += t;
            __syncthreads();
        }
        if (idx < n) psum[idx] = carry + lds[tid] - v;   // exclusive
        int total = lds[1023];
        __syncthreads();
        if (tid == 0) carry += total;
        __syncthreads();
    }
}

__global__ void k_scan3(int* __restrict__ out, const int* __restrict__ psum, int n) {
    int idx = blockIdx.x * 256 + threadIdx.x;
    if (idx < n) out[idx + 1] += psum[blockIdx.x];
    if (idx == 0) out[0] = 0;
}

__global__ void k_fill8(const int* __restrict__ ei, const int* __restrict__ et,
                        const int* __restrict__ rowptr2, int* __restrict__ cursor8,
                        int* __restrict__ eval) {
    int i = blockIdx.x * 256 + threadIdx.x;
    if (i >= N_EDGES) return;
    int seg = ei[N_EDGES + i] * N_REL + et[i];
    int pos = atomicAdd(&cursor8[seg], 1);
    eval[rowptr2[seg] + pos] = ei[i];          // src node only; relation implicit
}

// ---------- fused agg+GEMM (K=1152): out = relu([mean_r(feat) .. self] @ Wbig + bias) ----------
// BM=64: LDS As 16K + Bs 32K + meta 2K = 50K -> 3 blocks/CU. h-step r gathers
// relation-r edges of the block's 64 nodes directly into As (aggAll never materialized).
__global__ __launch_bounds__(256, 3) void k_gemm_fused_agg(
        const u16* __restrict__ feat,     // [N,128] bf16 (xc or h)
        const u16* __restrict__ B,        // [128][1152] bf16 (n-major, k contiguous)
        const u16* __restrict__ bias,     // [128]
        const int* __restrict__ rowptr2,  // [N*8+1] segment boundaries
        const int* __restrict__ eval,     // [E] src per edge, (dst,rel)-grouped
        u16* __restrict__ hout, void* __restrict__ fout,
        int final_out, const int* __restrict__ flag) {
    __shared__ u16 As[64 * 128];
    __shared__ u16 Bs[128 * 128];
    __shared__ int meta[513];
    int tid = threadIdx.x;
    int bm0 = blockIdx.x * 64;
    int wave = tid >> 6, lane = tid & 63;
    int wm = (wave & 1) * 32, wn = (wave >> 1) * 64;
    int lrow = lane & 15, quad = lane >> 4;
    int c2 = lane * 2;

    // stage segment boundaries for this block's 64 nodes (513 ints)
    for (int t = tid; t < 513; t += 256) {
        int gidx = bm0 * 8 + t;
        meta[t] = rowptr2[gidx > NSEG ? NSEG : gidx];
    }

    v4f accr[2][4];
    #pragma unroll
    for (int i = 0; i < 2; ++i)
        #pragma unroll
        for (int j = 0; j < 4; ++j) accr[i][j] = (v4f){0.f, 0.f, 0.f, 0.f};

    for (int h = 0; h < 9; ++h) {
        __syncthreads();                 // h=0: meta visible; h>0: WAR on As/Bs
        // stage B slice: 128x128 (8 int4/thread)
        #pragma unroll
        for (int it = 0; it < 8; ++it) {
            int c = it * 256 + tid;
            int row = c >> 4, cc = c & 15, swz = cc ^ (row & 15);
            int4 vb = *(const int4*)(B + (size_t)row * KDIM + h * 128 + cc * 8);
            *(int4*)(Bs + row * 128 + swz * 8) = vb;
        }
        if (h < 8) {
            // gather relation-h means for this wave's 16 nodes into As
            int i0 = wave * 16;
            #pragma unroll 2
            for (int t = 0; t < 16; ++t) {
                int il = i0 + t;
                int beg = meta[il * 8 + h], end = meta[il * 8 + h + 1];
                float fx = 0.f, fy = 0.f;
                for (int p = beg; p < end; ++p) {
                    int src = eval[p];
                    ushort2 u = *(const ushort2*)(feat + ((size_t)src << 7) + c2);
                    fx += bf2f(u.x); fy += bf2f(u.y);
                }
                int cnt = end - beg;
                float inv = 1.f / (float)(cnt > 0 ? cnt : 1);
                int chunk = lane >> 2;             // 16B chunk holding c2
                int swz = chunk ^ (il & 15);
                ushort2 o; o.x = f2bf(fx * inv); o.y = f2bf(fy * inv);
                *(ushort2*)(As + il * 128 + swz * 8 + (lane & 3) * 2) = o;
            }
        } else {
            // self slice: As = feat rows (4 int4/thread)
            #pragma unroll
            for (int it = 0; it < 4; ++it) {
                int c = it * 256 + tid;
                int row = c >> 4, cc = c & 15, swz = cc ^ (row & 15);
                int grow = bm0 + row;
                int4 va = make_int4(0, 0, 0, 0);
                if (grow < N_NODES) va = *(const int4*)(feat + (size_t)grow * 128 + cc * 8);
                *(int4*)(As + row * 128 + swz * 8) = va;
            }
        }
        __syncthreads();

        #pragma unroll
        for (int kk = 0; kk < 4; ++kk) {
            int chunk = kk * 4 + quad;
            int sw = (chunk ^ lrow) * 8;
            v8s a[2], b[4];
            #pragma unroll
            for (int t = 0; t < 2; ++t) a[t] = *(const v8s*)(As + (wm + t * 16 + lrow) * 128 + sw);
            #pragma unroll
            for (int t = 0; t < 4; ++t) b[t] = *(const v8s*)(Bs + (wn + t * 16 + lrow) * 128 + sw);
            #pragma unroll
            for (int ti = 0; ti < 2; ++ti)
                #pragma unroll
                for (int tj = 0; tj < 4; ++tj)
                    accr[ti][tj] = __builtin_amdgcn_mfma_f32_16x16x32_bf16(a[ti], b[tj], accr[ti][tj], 0, 0, 0);
        }
    }

    int fl = *flag;
    #pragma unroll
    for (int ti = 0; ti < 2; ++ti)
        #pragma unroll
        for (int reg = 0; reg < 4; ++reg) {
            int gm = bm0 + wm + ti * 16 + quad * 4 + reg;
            if (gm >= N_NODES) continue;
            #pragma unroll
            for (int tj = 0; tj < 4; ++tj) {
                int col = wn + tj * 16 + lrow;
                size_t idx = (size_t)gm * 128 + col;
                float v = fmaxf(accr[ti][tj][reg] + bf2f(bias[col]), 0.f);
                if (!final_out) hout[idx] = f2bf(v);
                else if (fl)    ((u16*)fout)[idx] = f2bf(v);
                else            ((float*)fout)[idx] = v;
            }
        }
}

__global__ void k_relemb(const void* __restrict__ src, void* __restrict__ out,
                         const int* __restrict__ flag) {
    int i = blockIdx.x * 256 + threadIdx.x;
    if (i >= N_REL * 128) return;
    size_t o = (size_t)N_NODES * 128 + i;
    if (*flag) ((u16*)out)[o]   = ((const u16*)src)[i];
    else       ((float*)out)[o] = ((const float*)src)[i];
}

// ---------------- launch ----------------
static inline size_t align_up(size_t x, size_t a) { return (x + a - 1) & ~(a - 1); }

extern "C" void kernel_launch(void* const* d_in, const int* in_sizes, int n_in,
                              void* d_out, int out_size, void* d_ws, size_t ws_size,
                              hipStream_t stream) {
    const int* ei = (const int*)d_in[1];
    const int* et = (const int*)d_in[2];

    char* ws = (char*)d_ws;
    size_t off = 0;
    int* flag     = (int*)(ws + off);  off = align_up(off + 4, 256);
    u16* Wbig     = (u16*)(ws + off);  off = align_up(off + (size_t)2 * 128 * KDIM * 2, 256);
    u16* bc       = (u16*)(ws + off);  off = align_up(off + 512, 256);
    u16* xc       = (u16*)(ws + off);  off = align_up(off + (size_t)N_NODES * 128 * 2, 256);
    int* cnt8     = (int*)(ws + off);  off += (size_t)NSEG * 4;      // cnt8+cursor8 contiguous zero
    int* cursor8  = (int*)(ws + off);  off = align_up(off + (size_t)NSEG * 4, 256);
    int* rowptr2  = (int*)(ws + off);  off = align_up(off + (size_t)(NSEG + 1) * 4, 256);
    int* psum     = (int*)(ws + off);  off = align_up(off + (size_t)NB_SEG * 4, 256);
    int* eval     = (int*)(ws + off);  off = align_up(off + (size_t)N_EDGES * 4, 256);
    u16* h        = (u16*)(ws + off);  off = align_up(off + (size_t)N_NODES * 128 * 2, 256);
    (void)in_sizes; (void)n_in; (void)out_size; (void)ws_size;       // ~33 MB total

    k_detect<<<1, 256, 0, stream>>>((const u32*)d_in[0], flag);
    k_convert<<<(N_NODES * 128 + 255) / 256, 256, 0, stream>>>(d_in[0], xc, N_NODES * 128, flag);
    k_prep_w<<<(2 * 128 * KDIM + 256 + 255) / 256, 256, 0, stream>>>(
        d_in[3], d_in[4], d_in[5], d_in[6], d_in[7], d_in[8], flag, Wbig, bc);

    k_zero_i32<<<(2 * NSEG + 255) / 256, 256, 0, stream>>>(cnt8, 2 * NSEG);
    k_count8<<<(N_EDGES + 255) / 256, 256, 0, stream>>>(ei, et, cnt8);
    k_scan1<<<NB_SEG, 256, 0, stream>>>(cnt8, rowptr2, psum, NSEG);
    k_scan2big<<<1, 1024, 0, stream>>>(psum, NB_SEG);
    k_scan3<<<NB_SEG, 256, 0, stream>>>(rowptr2, psum, NSEG);
    k_fill8<<<(N_EDGES + 255) / 256, 256, 0, stream>>>(ei, et, rowptr2, cursor8, eval);

    int ggrid = (N_NODES + 63) / 64;    // 782
    for (int l = 0; l < 2; ++l) {
        const u16* src = l ? h : xc;
        k_gemm_fused_agg<<<ggrid, 256, 0, stream>>>(src, Wbig + (size_t)l * 128 * KDIM,
                                                    bc + l * 128, rowptr2, eval,
                                                    h, d_out, l, flag);
    }
    k_relemb<<<4, 256, 0, stream>>>(d_in[9], d_out, flag);
}

// Round 7
// 435.257 us; speedup vs baseline: 1.5605x; 1.5605x over previous
//
#include <hip/hip_runtime.h>
#include <stdint.h>

#define N_NODES 50000
#define N_EDGES 600000
#define N_REL   8
#define KDIM    1152                      // 8*128 relation means + 128 self/root
#define NB_SCAN ((N_NODES + 255) / 256)   // 196

typedef short v8s __attribute__((ext_vector_type(8)));
typedef float v4f __attribute__((ext_vector_type(4)));
typedef unsigned short u16;
typedef unsigned int   u32;

__device__ __forceinline__ float bf2f(u16 u) {
    union { u32 i; float f; } t; t.i = ((u32)u) << 16; return t.f;
}
__device__ __forceinline__ u16 f2bf(float f) {
    union { float f; u32 i; } t; t.f = f;
    u32 lsb = (t.i >> 16) & 1u;
    t.i += 0x7fffu + lsb;            // round-to-nearest-even
    return (u16)(t.i >> 16);
}
__device__ __forceinline__ float load_f(const void* p, int i, int fl) {
    return fl ? bf2f(((const u16*)p)[i]) : ((const float*)p)[i];
}

// ---------- dtype detection ----------
__global__ void k_detect(const u32* __restrict__ x, int* __restrict__ flag) {
    __shared__ int cnt;
    int tid = threadIdx.x;
    if (tid == 0) cnt = 0;
    __syncthreads();
    int local = 0;
    for (int j = 0; j < 4; ++j) {
        u32 e = (x[tid * 4 + j] >> 7) & 0xffu;
        if (e >= 112u && e < 144u) local++;
    }
    atomicAdd(&cnt, local);
    __syncthreads();
    if (tid == 0) *flag = (cnt >= 512) ? 1 : 0;   // 1 = bf16, 0 = f32
}

__global__ void k_convert(const void* __restrict__ src, u16* __restrict__ dst, int n,
                          const int* __restrict__ flag) {
    int i = blockIdx.x * 256 + threadIdx.x;
    if (i >= n) return;
    if (*flag) dst[i] = ((const u16*)src)[i];
    else       dst[i] = f2bf(((const float*)src)[i]);
}

// ---------- weight prep ----------
// Wbig[l][j][k]: k<1024 -> W_l[k/128][k%128][j]; k>=1024 -> root_l[k-1024][j]
__global__ void k_prep_w(const void* __restrict__ W1, const void* __restrict__ r1,
                         const void* __restrict__ b1, const void* __restrict__ W2,
                         const void* __restrict__ r2, const void* __restrict__ b2,
                         const int* __restrict__ flag,
                         u16* __restrict__ Wbig, u16* __restrict__ bc) {
    int o = blockIdx.x * 256 + threadIdx.x;
    int fl = *flag;
    if (o < 2 * 128 * KDIM) {
        int l = o / (128 * KDIM);
        int rem = o - l * (128 * KDIM);
        int j = rem / KDIM, k = rem - j * KDIM;
        float v;
        if (k < 1024) {
            int r = k >> 7, kk = k & 127;
            v = load_f(l ? W2 : W1, r * 16384 + kk * 128 + j, fl);
        } else {
            v = load_f(l ? r2 : r1, (k - 1024) * 128 + j, fl);
        }
        Wbig[o] = f2bf(v);
    } else if (o < 2 * 128 * KDIM + 256) {
        int o2 = o - 2 * 128 * KDIM;
        bc[o2] = f2bf(load_f((o2 >> 7) ? b2 : b1, o2 & 127, fl));
    }
}

// ---------- graph prep: per-node CSR, eval = (src<<3)|et ----------
__global__ void k_zero_i32(int* __restrict__ p, int n) {
    int i = blockIdx.x * 256 + threadIdx.x;
    if (i < n) p[i] = 0;
}

__global__ void k_count(const int* __restrict__ ei, int* __restrict__ deg) {
    int i = blockIdx.x * 256 + threadIdx.x;
    if (i >= N_EDGES) return;
    atomicAdd(&deg[ei[N_EDGES + i]], 1);
}

__global__ void k_scan1(const int* __restrict__ deg, int* __restrict__ rowptr,
                        int* __restrict__ psum) {
    __shared__ int lds[256];
    int tid = threadIdx.x;
    int idx = blockIdx.x * 256 + tid;
    int v = (idx < N_NODES) ? deg[idx] : 0;
    lds[tid] = v;
    __syncthreads();
    for (int off = 1; off < 256; off <<= 1) {
        int t = (tid >= off) ? lds[tid - off] : 0;
        __syncthreads();
        lds[tid] += t;
        __syncthreads();
    }
    if (idx < N_NODES) rowptr[idx + 1] = lds[tid];
    if (tid == 255) psum[blockIdx.x] = lds[255];
}

__global__ void k_scan2(int* __restrict__ psum) {
    __shared__ int lds[256];
    int tid = threadIdx.x;
    int v = (tid < NB_SCAN) ? psum[tid] : 0;
    lds[tid] = v;
    __syncthreads();
    for (int off = 1; off < 256; off <<= 1) {
        int t = (tid >= off) ? lds[tid - off] : 0;
        __syncthreads();
        lds[tid] += t;
        __syncthreads();
    }
    if (tid < NB_SCAN) psum[tid] = lds[tid] - v;   // exclusive
}

__global__ void k_scan3(int* __restrict__ rowptr, const int* __restrict__ psum) {
    int idx = blockIdx.x * 256 + threadIdx.x;
    if (idx < N_NODES) rowptr[idx + 1] += psum[blockIdx.x];
    if (idx == 0) rowptr[0] = 0;
}

__global__ void k_fill(const int* __restrict__ ei, const int* __restrict__ et,
                       const int* __restrict__ rowptr, int* __restrict__ cursor,
                       int* __restrict__ eval) {
    int i = blockIdx.x * 256 + threadIdx.x;
    if (i >= N_EDGES) return;
    int d = ei[N_EDGES + i];
    int pos = atomicAdd(&cursor[d], 1);
    eval[rowptr[d] + pos] = (ei[i] << 3) | et[i];
}

// ---------- fused agg+GEMM, BM=16 ----------
// Phase 1: wave-per-node gather (round-5 structure: one pass over the node's
//   edge list, x4 unrolled, 8 relation accumulators in registers) -> means
//   written to LDS As[16][1024] (XOR-swizzled). Self/root slice via 4
//   prefetched global fragments (no LDS).
// Phase 2: K=1152 MFMA with B streamed through 16 KB LDS chunks.
// LDS 48 KB -> 3 blocks/CU (12 waves): gathers of co-resident blocks overlap
// other blocks' GEMM phases.
#define ACC_EDGE(EV, UX, UY) do {                                          \
    int r_ = (EV) & 7; float fx_ = bf2f(UX), fy_ = bf2f(UY);               \
    switch (r_) {                                                          \
    case 0: s0x += fx_; s0y += fy_; c0++; break;                           \
    case 1: s1x += fx_; s1y += fy_; c1++; break;                           \
    case 2: s2x += fx_; s2y += fy_; c2_++; break;                          \
    case 3: s3x += fx_; s3y += fy_; c3++; break;                           \
    case 4: s4x += fx_; s4y += fy_; c4++; break;                           \
    case 5: s5x += fx_; s5y += fy_; c5++; break;                           \
    case 6: s6x += fx_; s6y += fy_; c6++; break;                           \
    default: s7x += fx_; s7y += fy_; c7++; break;                          \
    } } while (0)

__global__ __launch_bounds__(256, 3) void k_fused(
        const u16* __restrict__ feat,     // [N,128] bf16 (xc or h)
        const u16* __restrict__ B,        // [128][1152] bf16 (j-major, k contiguous)
        const u16* __restrict__ bias,     // [128]
        const int* __restrict__ rowptr, const int* __restrict__ eval,
        u16* __restrict__ hout, void* __restrict__ fout,
        int final_out, const int* __restrict__ flag) {
    __shared__ __align__(16) u16 As[16 * 1024];   // 32 KB
    __shared__ __align__(16) u16 Bs[128 * 64];    // 16 KB
    int tid = threadIdx.x, wave = tid >> 6, lane = tid & 63;
    int lrow = lane & 15, quad = lane >> 4;
    int bm0 = blockIdx.x * 16;
    int c2 = lane * 2;

    // prefetch self/root fragments (consumed at kc=16,17)
    v8s a_self[2][2];
    #pragma unroll
    for (int i = 0; i < 2; ++i)
        #pragma unroll
        for (int s2 = 0; s2 < 2; ++s2)
            a_self[i][s2] = *(const v8s*)(feat + (size_t)(bm0 + lrow) * 128 +
                                          i * 64 + s2 * 32 + quad * 8);

    // ---- phase 1: gather means into As ----
    for (int t = 0; t < 4; ++t) {
        int il = wave * 4 + t;
        int node = bm0 + il;
        float s0x=0,s0y=0,s1x=0,s1y=0,s2x=0,s2y=0,s3x=0,s3y=0;
        float s4x=0,s4y=0,s5x=0,s5y=0,s6x=0,s6y=0,s7x=0,s7y=0;
        int c0=0,c1=0,c2_=0,c3=0,c4=0,c5=0,c6=0,c7=0;
        int s = rowptr[node], e = rowptr[node + 1];
        int i = s;
        for (; i + 3 < e; i += 4) {
            int ev0 = eval[i], ev1 = eval[i+1], ev2 = eval[i+2], ev3 = eval[i+3];
            ushort2 u0 = *(const ushort2*)(feat + ((size_t)(ev0 >> 3) << 7) + c2);
            ushort2 u1 = *(const ushort2*)(feat + ((size_t)(ev1 >> 3) << 7) + c2);
            ushort2 u2 = *(const ushort2*)(feat + ((size_t)(ev2 >> 3) << 7) + c2);
            ushort2 u3 = *(const ushort2*)(feat + ((size_t)(ev3 >> 3) << 7) + c2);
            ACC_EDGE(ev0, u0.x, u0.y);
            ACC_EDGE(ev1, u1.x, u1.y);
            ACC_EDGE(ev2, u2.x, u2.y);
            ACC_EDGE(ev3, u3.x, u3.y);
        }
        for (; i < e; ++i) {
            int ev0 = eval[i];
            ushort2 u0 = *(const ushort2*)(feat + ((size_t)(ev0 >> 3) << 7) + c2);
            ACC_EDGE(ev0, u0.x, u0.y);
        }
        // write 8 slices: element col = r*128 + c2; chunk = r*16 + ((lane>>2)^il)
        int swz = (lane >> 2) ^ il;
        u16* d = As + il * 1024 + swz * 8 + (lane & 3) * 2;
        float inv; ushort2 o;
        inv = 1.f/(float)(c0 >0?c0 :1); o.x=f2bf(s0x*inv); o.y=f2bf(s0y*inv); *(ushort2*)(d)           = o;
        inv = 1.f/(float)(c1 >0?c1 :1); o.x=f2bf(s1x*inv); o.y=f2bf(s1y*inv); *(ushort2*)(d + 1*128)   = o;
        inv = 1.f/(float)(c2_>0?c2_:1); o.x=f2bf(s2x*inv); o.y=f2bf(s2y*inv); *(ushort2*)(d + 2*128)   = o;
        inv = 1.f/(float)(c3 >0?c3 :1); o.x=f2bf(s3x*inv); o.y=f2bf(s3y*inv); *(ushort2*)(d + 3*128)   = o;
        inv = 1.f/(float)(c4 >0?c4 :1); o.x=f2bf(s4x*inv); o.y=f2bf(s4y*inv); *(ushort2*)(d + 4*128)   = o;
        inv = 1.f/(float)(c5 >0?c5 :1); o.x=f2bf(s5x*inv); o.y=f2bf(s5y*inv); *(ushort2*)(d + 5*128)   = o;
        inv = 1.f/(float)(c6 >0?c6 :1); o.x=f2bf(s6x*inv); o.y=f2bf(s6y*inv); *(ushort2*)(d + 6*128)   = o;
        inv = 1.f/(float)(c7 >0?c7 :1); o.x=f2bf(s7x*inv); o.y=f2bf(s7y*inv); *(ushort2*)(d + 7*128)   = o;
    }
    __syncthreads();

    // ---- phase 2: K=1152 GEMM, B streamed in 18 chunks of [128][64] ----
    v4f acc[2];
    acc[0] = (v4f){0.f, 0.f, 0.f, 0.f};
    acc[1] = (v4f){0.f, 0.f, 0.f, 0.f};

    for (int kc = 0; kc < 18; ++kc) {
        if (kc) __syncthreads();          // WAR on Bs
        #pragma unroll
        for (int it = 0; it < 4; ++it) {
            int c = it * 256 + tid;       // 0..1023
            int row = c >> 3, cc = c & 7;
            int sw = cc ^ (row & 7);
            *(int4*)(Bs + row * 64 + sw * 8) =
                *(const int4*)(B + (size_t)row * KDIM + kc * 64 + cc * 8);
        }
        __syncthreads();

        #pragma unroll
        for (int sub = 0; sub < 2; ++sub) {
            v8s a;
            if (kc < 16) {
                int c4 = kc * 8 + sub * 4 + quad;           // 16B-chunk 0..127
                int sw = (c4 & ~15) | ((c4 ^ lrow) & 15);
                a = *(const v8s*)(As + lrow * 1024 + sw * 8);
            } else {
                a = a_self[kc - 16][sub];
            }
            #pragma unroll
            for (int tj = 0; tj < 2; ++tj) {
                int row = wave * 32 + tj * 16 + lrow;
                int ch = (sub * 4 + quad) ^ (lrow & 7);
                v8s b = *(const v8s*)(Bs + row * 64 + ch * 8);
                acc[tj] = __builtin_amdgcn_mfma_f32_16x16x32_bf16(a, b, acc[tj], 0, 0, 0);
            }
        }
    }

    // ---- epilogue ----
    int fl = *flag;
    #pragma unroll
    for (int tj = 0; tj < 2; ++tj)
        #pragma unroll
        for (int reg = 0; reg < 4; ++reg) {
            int gm = bm0 + quad * 4 + reg;            // N_NODES % 16 == 0: no guard
            int col = wave * 32 + tj * 16 + lrow;
            size_t idx = (size_t)gm * 128 + col;
            float v = fmaxf(acc[tj][reg] + bf2f(bias[col]), 0.f);
            if (!final_out) hout[idx] = f2bf(v);
            else if (fl)    ((u16*)fout)[idx] = f2bf(v);
            else            ((float*)fout)[idx] = v;
        }
}

__global__ void k_relemb(const void* __restrict__ src, void* __restrict__ out,
                         const int* __restrict__ flag) {
    int i = blockIdx.x * 256 + threadIdx.x;
    if (i >= N_REL * 128) return;
    size_t o = (size_t)N_NODES * 128 + i;
    if (*flag) ((u16*)out)[o]   = ((const u16*)src)[i];
    else       ((float*)out)[o] = ((const float*)src)[i];
}

// ---------------- launch ----------------
static inline size_t align_up(size_t x, size_t a) { return (x + a - 1) & ~(a - 1); }

extern "C" void kernel_launch(void* const* d_in, const int* in_sizes, int n_in,
                              void* d_out, int out_size, void* d_ws, size_t ws_size,
                              hipStream_t stream) {
    const int* ei = (const int*)d_in[1];
    const int* et = (const int*)d_in[2];

    char* ws = (char*)d_ws;
    size_t off = 0;
    int* flag    = (int*)(ws + off);  off = align_up(off + 4, 256);
    u16* Wbig    = (u16*)(ws + off);  off = align_up(off + (size_t)2 * 128 * KDIM * 2, 256);
    u16* bc      = (u16*)(ws + off);  off = align_up(off + 512, 256);
    u16* xc      = (u16*)(ws + off);  off = align_up(off + (size_t)N_NODES * 128 * 2, 256);
    int* deg     = (int*)(ws + off);  off += (size_t)N_NODES * 4;    // deg+cursor contiguous zero
    int* cursor  = (int*)(ws + off);  off = align_up(off + (size_t)N_NODES * 4, 256);
    int* rowptr  = (int*)(ws + off);  off = align_up(off + (size_t)(N_NODES + 1) * 4, 256);
    int* psum    = (int*)(ws + off);  off = align_up(off + (size_t)NB_SCAN * 4, 256);
    int* eval    = (int*)(ws + off);  off = align_up(off + (size_t)N_EDGES * 4, 256);
    u16* h       = (u16*)(ws + off);  off = align_up(off + (size_t)N_NODES * 128 * 2, 256);
    (void)in_sizes; (void)n_in; (void)out_size; (void)ws_size;       // ~29 MB total

    k_detect<<<1, 256, 0, stream>>>((const u32*)d_in[0], flag);
    k_convert<<<(N_NODES * 128 + 255) / 256, 256, 0, stream>>>(d_in[0], xc, N_NODES * 128, flag);
    k_prep_w<<<(2 * 128 * KDIM + 256 + 255) / 256, 256, 0, stream>>>(
        d_in[3], d_in[4], d_in[5], d_in[6], d_in[7], d_in[8], flag, Wbig, bc);

    k_zero_i32<<<(2 * N_NODES + 255) / 256, 256, 0, stream>>>(deg, 2 * N_NODES);
    k_count<<<(N_EDGES + 255) / 256, 256, 0, stream>>>(ei, deg);
    k_scan1<<<NB_SCAN, 256, 0, stream>>>(deg, rowptr, psum);
    k_scan2<<<1, 256, 0, stream>>>(psum);
    k_scan3<<<NB_SCAN, 256, 0, stream>>>(rowptr, psum);
    k_fill<<<(N_EDGES + 255) / 256, 256, 0, stream>>>(ei, et, rowptr, cursor, eval);

    int ggrid = N_NODES / 16;           // 3125, exact
    for (int l = 0; l < 2; ++l) {
        const u16* src = l ? h : xc;
        k_fused<<<ggrid, 256, 0, stream>>>(src, Wbig + (size_t)l * 128 * KDIM,
                                           bc + l * 128, rowptr, eval,
                                           h, d_out, l, flag);
    }
    k_relemb<<<4, 256, 0, stream>>>(d_in[9], d_out, flag);
}